// Round 5
// baseline (292.387 us; speedup 1.0000x reference)
//
#include <hip/hip_runtime.h>
#include <stdint.h>

// Problem constants (match reference)
#define N_PRIORS 2097152
#define KTOP 512
#define NBINS 2048
#define K1BLK 2048
#define SCAP 32                  // stash slots per k1 block (mean 0.39, Poisson-safe)
#define SELCAP 2048
#define SSTASH 0.9915f           // stash pre-filter; expected ~800 >= 512 (10 sigma)

// ws layout: [0, 8K) u32 blk_cnt[2048]; [8K, 8K+512K) u64 stash[2048*32]

__device__ __forceinline__ uint64_t pack_key(float s, int idx) {
    // descending score, ascending index tie-break (== stable top_k)
    return ((uint64_t)__float_as_uint(s) << 32) | (uint32_t)(~idx);
}

__device__ __forceinline__ float score_of(float c0, float c1) {
    #pragma clang fp contract(off)
    float m  = fmaxf(c0, c1);
    float e0 = expf(c0 - m);
    float e1 = expf(c1 - m);
    return e1 / (e0 + e1);
}

__device__ __forceinline__ int bin_of(float s) {
    #pragma clang fp contract(off)
    int b = (int)((s - 0.9f) * 20480.0f);   // 2048 bins over (0.9, 1.0]
    return b > (NBINS - 1) ? (NBINS - 1) : b;
}

__device__ __forceinline__ int wave_min(int v) {
    #pragma unroll
    for (int m = 1; m < 64; m <<= 1) { int o = __shfl_xor(v, m); v = o < v ? o : v; }
    return v;
}

// K1: stream conf once (full grid); stash s > SSTASH into per-block regions.
// Zero global atomics; LDS counter only.
__global__ void k1_stash(const float4* __restrict__ conf4,
                         uint32_t* __restrict__ blk_cnt,
                         uint64_t* __restrict__ stash) {
    #pragma clang fp contract(off)
    __shared__ uint32_t lcnt;
    int t = threadIdx.x;            // 256 threads
    int blk = blockIdx.x;           // 2048 blocks, 512 float4 (1024 elems) each
    if (t == 0) lcnt = 0;
    __syncthreads();
    uint64_t* reg = stash + (size_t)blk * SCAP;
    #pragma unroll
    for (int i = 0; i < 2; ++i) {
        int f4i = blk * 512 + t + 256 * i;
        float4 c = conf4[f4i];
        float s0 = score_of(c.x, c.y);
        float s1 = score_of(c.z, c.w);
        if (s0 > SSTASH) {
            uint32_t p = atomicAdd(&lcnt, 1u);
            if (p < SCAP) reg[p] = pack_key(s0, f4i * 2);
        }
        if (s1 > SSTASH) {
            uint32_t p = atomicAdd(&lcnt, 1u);
            if (p < SCAP) reg[p] = pack_key(s1, f4i * 2 + 1);
        }
    }
    __syncthreads();
    if (t == 0) blk_cnt[blk] = (lcnt <= SCAP) ? lcnt : 0xFFFFFFFFu;
}

// K2: single block: gather stash -> sort -> decode -> LAZY greedy NMS -> out.
__launch_bounds__(1024)
__global__ void k2_finish(const float4* __restrict__ loc,
                          const float4* __restrict__ priors,
                          const float4* __restrict__ conf4,
                          const uint32_t* __restrict__ blk_cnt,
                          const uint64_t* __restrict__ stash,
                          float* __restrict__ out) {
    #pragma clang fp contract(off)
    __shared__ uint64_t sel[SELCAP];        // 16 KB
    __shared__ uint32_t hist[NBINS];        // 8 KB (fallback only)
    __shared__ float4 bpk[KTOP];            // 8 KB pixel boxes
    __shared__ float  sar[KTOP], ssc[KTOP]; // 4 KB
    __shared__ uint8_t keepB[KTOP];         // 512 B
    __shared__ uint32_t nselS, fbS;
    __shared__ int bmaxS;

    int tid = threadIdx.x;          // 1024 threads
    int lane = tid & 63;

    if (tid == 0) { nselS = 0u; fbS = 0u; bmaxS = 0; }
    __syncthreads();

    // ---- gather stash entries (breadth-first, ~800 expected) ----
    for (int b = tid; b < K1BLK; b += 1024) {
        uint32_t c = blk_cnt[b];
        if (c == 0xFFFFFFFFu) { atomicOr(&fbS, 1u); c = 0; }
        const uint64_t* regp = stash + (size_t)b * SCAP;
        for (uint32_t j = 0; j < c; ++j) {
            uint64_t k = regp[j];
            uint32_t p = atomicAdd(&nselS, 1u);
            if (p < SELCAP) sel[p] = k; else atomicOr(&fbS, 1u);
        }
    }
    __syncthreads();
    uint32_t n = nselS;
    bool fb = (fbS != 0u) || (n < KTOP) || (n > SELCAP);
    __syncthreads();

    if (fb) {
        // ---- exact fallback: 2-pass histogram select over all of conf ----
        if (tid == 0) nselS = 0u;
        for (int b = tid; b < NBINS; b += 1024) hist[b] = 0u;
        __syncthreads();
        for (int f = tid; f < N_PRIORS / 2; f += 1024) {
            float4 c = conf4[f];
            float s0 = score_of(c.x, c.y);
            float s1 = score_of(c.z, c.w);
            if (s0 > 0.9f) atomicAdd(&hist[bin_of(s0)], 1u);
            if (s1 > 0.9f) atomicAdd(&hist[bin_of(s1)], 1u);
        }
        __syncthreads();
        for (int off = 1; off < NBINS; off <<= 1) {
            int b0 = tid, b1 = tid + 1024;
            uint32_t v0 = hist[b0] + ((b0 + off < NBINS) ? hist[b0 + off] : 0u);
            uint32_t v1 = hist[b1] + ((b1 + off < NBINS) ? hist[b1 + off] : 0u);
            __syncthreads();
            hist[b0] = v0; hist[b1] = v1;
            __syncthreads();
        }
        if (hist[tid] >= KTOP) atomicMax(&bmaxS, tid);
        if (hist[tid + 1024] >= KTOP) atomicMax(&bmaxS, tid + 1024);
        __syncthreads();
        int B = bmaxS;
        for (int f = tid; f < N_PRIORS / 2; f += 1024) {
            float4 c = conf4[f];
            float s0 = score_of(c.x, c.y);
            float s1 = score_of(c.z, c.w);
            if (s0 > 0.9f && bin_of(s0) >= B) {
                uint32_t p = atomicAdd(&nselS, 1u);
                if (p < SELCAP) sel[p] = pack_key(s0, 2 * f);
            }
            if (s1 > 0.9f && bin_of(s1) >= B) {
                uint32_t p = atomicAdd(&nselS, 1u);
                if (p < SELCAP) sel[p] = pack_key(s1, 2 * f + 1);
            }
        }
        __syncthreads();
        n = nselS; if (n > SELCAP) n = SELCAP;
        __syncthreads();
    }

    int P = KTOP; while (P < (int)n) P <<= 1;
    for (int t = tid; t < P; t += 1024) if (t >= (int)n) sel[t] = 0ull;
    __syncthreads();

    // ---- bitonic sort, descending (0-padding sinks) ----
    for (int k = 2; k <= P; k <<= 1) {
        for (int j = k >> 1; j > 0; j >>= 1) {
            for (int t = tid; t < P; t += 1024) {
                int ixj = t ^ j;
                if (ixj > t) {
                    uint64_t a = sel[t], b = sel[ixj];
                    bool sw = ((t & k) == 0) ? (a < b) : (a > b);
                    if (sw) { sel[t] = b; sel[ixj] = a; }
                }
            }
            __syncthreads();
        }
    }

    // ---- decode top-512 (exact numpy op order) ----
    if (tid < KTOP) {
        uint64_t key = sel[tid];
        float4 bb; float area, sc; uint8_t kp;
        if (key != 0ull) {
            sc = __uint_as_float((uint32_t)(key >> 32));
            int idx  = (int)(~(uint32_t)key);
            float4 l = loc[idx];
            float4 p = priors[idx];
            float cx = p.x + (l.x * 0.1f) * p.z;
            float cy = p.y + (l.y * 0.1f) * p.w;
            float w  = p.z * expf(l.z * 0.2f);
            float h  = p.w * expf(l.w * 0.2f);
            float x1 = cx - w * 0.5f;
            float y1 = cy - h * 0.5f;
            float x2 = x1 + w;
            float y2 = y1 + h;
            x1 *= 2048.0f; y1 *= 2048.0f; x2 *= 2048.0f; y2 *= 2048.0f;
            bb = make_float4(x1, y1, x2, y2);
            area = (x2 - x1 + 1.0f) * (y2 - y1 + 1.0f);
            kp = 1;
        } else {
            bb = make_float4(0.f, 0.f, 0.f, 0.f); area = 1.f; sc = 0.f; kp = 0;
        }
        bpk[tid] = bb; sar[tid] = area; ssc[tid] = sc; keepB[tid] = kp;
    }
    __syncthreads();

    // ---- LAZY greedy NMS: one wave, keep-bits in registers (8 cols/lane),
    //      only actually-kept rows (~tens) compute their 512 IoUs ----
    if (tid < 64) {
        float4 cb0 = bpk[lane * 8 + 0], cb1 = bpk[lane * 8 + 1];
        float4 cb2 = bpk[lane * 8 + 2], cb3 = bpk[lane * 8 + 3];
        float4 cb4 = bpk[lane * 8 + 4], cb5 = bpk[lane * 8 + 5];
        float4 cb6 = bpk[lane * 8 + 6], cb7 = bpk[lane * 8 + 7];
        // identical formula+inputs as decode -> bit-identical areas
        float ca0 = (cb0.z - cb0.x + 1.0f) * (cb0.w - cb0.y + 1.0f);
        float ca1 = (cb1.z - cb1.x + 1.0f) * (cb1.w - cb1.y + 1.0f);
        float ca2 = (cb2.z - cb2.x + 1.0f) * (cb2.w - cb2.y + 1.0f);
        float ca3 = (cb3.z - cb3.x + 1.0f) * (cb3.w - cb3.y + 1.0f);
        float ca4 = (cb4.z - cb4.x + 1.0f) * (cb4.w - cb4.y + 1.0f);
        float ca5 = (cb5.z - cb5.x + 1.0f) * (cb5.w - cb5.y + 1.0f);
        float ca6 = (cb6.z - cb6.x + 1.0f) * (cb6.w - cb6.y + 1.0f);
        float ca7 = (cb7.z - cb7.x + 1.0f) * (cb7.w - cb7.y + 1.0f);
        uint32_t rk = 0u;
        #pragma unroll
        for (int c = 0; c < 8; ++c) rk |= ((uint32_t)keepB[lane * 8 + c]) << c;

        // next kept index > i (wave-parallel)
        #define NEXT_I(iv, res) do { int nc = 1024; \
            _Pragma("unroll") for (int c = 0; c < 8; ++c) { \
                int col = lane * 8 + c; \
                if (((rk >> c) & 1u) && col > (iv) && col < nc) nc = col; } \
            (res) = wave_min(nc); } while (0)

        #define NMSC(c, CB, CA) do { \
            float xx1 = fmaxf(rb.x, CB.x); float yy1 = fmaxf(rb.y, CB.y); \
            float xx2 = fminf(rb.z, CB.z); float yy2 = fminf(rb.w, CB.w); \
            float ww = fmaxf(xx2 - xx1 + 1.0f, 0.0f); \
            float hh = fmaxf(yy2 - yy1 + 1.0f, 0.0f); \
            float inter = ww * hh; \
            float iou = inter / (ra + (CA) - inter); \
            if (iou > 0.4f && (lane * 8 + (c)) > i) rk &= ~(1u << (c)); } while (0)

        int i; NEXT_I(-1, i);
        while (i < KTOP) {
            float4 rb = bpk[i];   // wave-uniform broadcast
            float ra = sar[i];
            NMSC(0, cb0, ca0); NMSC(1, cb1, ca1); NMSC(2, cb2, ca2); NMSC(3, cb3, ca3);
            NMSC(4, cb4, ca4); NMSC(5, cb5, ca5); NMSC(6, cb6, ca6); NMSC(7, cb7, ca7);
            int ni; NEXT_I(i, ni); i = ni;
        }
        #undef NMSC
        #undef NEXT_I
        #pragma unroll
        for (int c = 0; c < 8; ++c) keepB[lane * 8 + c] = (uint8_t)((rk >> c) & 1u);
    }
    __syncthreads();

    // ---- epilogue: [512,5], boxes /2048 (exact pow2), zeros if suppressed ----
    if (tid < KTOP) {
        const float inv = 1.0f / 2048.0f;
        float4 bb = bpk[tid];
        float* o = out + tid * 5;
        if (keepB[tid]) {
            o[0] = bb.x * inv;
            o[1] = bb.y * inv;
            o[2] = bb.z * inv;
            o[3] = bb.w * inv;
            o[4] = ssc[tid];
        } else {
            o[0] = 0.f; o[1] = 0.f; o[2] = 0.f; o[3] = 0.f; o[4] = 0.f;
        }
    }
}

extern "C" void kernel_launch(void* const* d_in, const int* in_sizes, int n_in,
                              void* d_out, int out_size, void* d_ws, size_t ws_size,
                              hipStream_t stream) {
    const float* loc    = (const float*)d_in[0];   // [1,N,4]
    const float* conf   = (const float*)d_in[1];   // [1,N,2]
    const float* priors = (const float*)d_in[2];   // [N,4]
    float* out = (float*)d_out;                    // [512,5]

    uint8_t* ws = (uint8_t*)d_ws;
    uint32_t* blk_cnt = (uint32_t*)ws;             // 8 KB
    uint64_t* stash   = (uint64_t*)(ws + 8192);    // 512 KB

    // no memset needed: blk_cnt fully written by K1; everything else is LDS
    k1_stash<<<K1BLK, 256, 0, stream>>>((const float4*)conf, blk_cnt, stash);
    k2_finish<<<1, 1024, 0, stream>>>((const float4*)loc, (const float4*)priors,
                                      (const float4*)conf, blk_cnt, stash, out);
}

// Round 6
// 177.739 us; speedup vs baseline: 1.6450x; 1.6450x over previous
//
#include <hip/hip_runtime.h>
#include <stdint.h>

// Problem constants (match reference)
#define N_PRIORS 2097152
#define KTOP 512
#define NBINS 2048
#define K1BLK 2048
#define SCAP 32                  // stash slots per k1 block (mean 0.39, Poisson-safe)
#define SELCAP 2048
#define SSTASH 0.9915f           // stash pre-filter; expected ~800 >= 512 (10 sigma)

// ws layout: [0, 8K) u32 blk_cnt[2048]; [8K, 8K+512K) u64 stash[2048*32]

__device__ __forceinline__ uint64_t pack_key(float s, int idx) {
    // descending score, ascending index tie-break (== stable top_k)
    return ((uint64_t)__float_as_uint(s) << 32) | (uint32_t)(~idx);
}

__device__ __forceinline__ float score_of(float c0, float c1) {
    #pragma clang fp contract(off)
    float m  = fmaxf(c0, c1);
    float e0 = expf(c0 - m);
    float e1 = expf(c1 - m);
    return e1 / (e0 + e1);
}

__device__ __forceinline__ int bin_of(float s) {
    #pragma clang fp contract(off)
    int b = (int)((s - 0.9f) * 20480.0f);   // 2048 bins over (0.9, 1.0]
    return b > (NBINS - 1) ? (NBINS - 1) : b;
}

// K1: stream conf once (full grid); stash s > SSTASH into per-block regions.
// Zero global atomics; LDS counter only.
__global__ void k1_stash(const float4* __restrict__ conf4,
                         uint32_t* __restrict__ blk_cnt,
                         uint64_t* __restrict__ stash) {
    #pragma clang fp contract(off)
    __shared__ uint32_t lcnt;
    int t = threadIdx.x;            // 256 threads
    int blk = blockIdx.x;           // 2048 blocks, 512 float4 (1024 elems) each
    if (t == 0) lcnt = 0;
    __syncthreads();
    uint64_t* reg = stash + (size_t)blk * SCAP;
    #pragma unroll
    for (int i = 0; i < 2; ++i) {
        int f4i = blk * 512 + t + 256 * i;
        float4 c = conf4[f4i];
        float s0 = score_of(c.x, c.y);
        float s1 = score_of(c.z, c.w);
        if (s0 > SSTASH) {
            uint32_t p = atomicAdd(&lcnt, 1u);
            if (p < SCAP) reg[p] = pack_key(s0, f4i * 2);
        }
        if (s1 > SSTASH) {
            uint32_t p = atomicAdd(&lcnt, 1u);
            if (p < SCAP) reg[p] = pack_key(s1, f4i * 2 + 1);
        }
    }
    __syncthreads();
    if (t == 0) blk_cnt[blk] = (lcnt <= SCAP) ? lcnt : 0xFFFFFFFFu;
}

// K2: single block: gather stash -> sort -> decode -> parallel suppression
// matrix (ballot bitmasks) -> greedy bitmask scan -> out.
__launch_bounds__(1024)
__global__ void k2_finish(const float4* __restrict__ loc,
                          const float4* __restrict__ priors,
                          const float4* __restrict__ conf4,
                          const uint32_t* __restrict__ blk_cnt,
                          const uint64_t* __restrict__ stash,
                          float* __restrict__ out) {
    #pragma clang fp contract(off)
    __shared__ uint64_t arena[4096];        // 32 KB: sel[0..2048) then supW[512][8]
    uint64_t* sel  = arena;                 // dead after decode
    uint64_t* supW = arena;                 // [r*8 + c] bit L = col 64c+L suppressed
    __shared__ uint32_t hist[NBINS];        // 8 KB (fallback only)
    __shared__ float4 bpk[KTOP];            // 8 KB pixel boxes
    __shared__ float  sar[KTOP], ssc[KTOP]; // 4 KB
    __shared__ uint64_t keepw0[8];          // valid bits (pre-NMS)
    __shared__ uint64_t keepw[8];           // final keep bits
    __shared__ uint32_t rowany32[16];
    __shared__ uint32_t nselS, fbS;
    __shared__ int bmaxS;

    int tid = threadIdx.x;          // 1024 threads
    int lane = tid & 63, wv = tid >> 6;

    if (tid == 0) { nselS = 0u; fbS = 0u; bmaxS = 0; }
    if (tid < 16) rowany32[tid] = 0u;
    __syncthreads();

    // ---- gather stash entries (breadth-first, ~800 expected) ----
    for (int b = tid; b < K1BLK; b += 1024) {
        uint32_t c = blk_cnt[b];
        if (c == 0xFFFFFFFFu) { atomicOr(&fbS, 1u); c = 0; }
        const uint64_t* regp = stash + (size_t)b * SCAP;
        for (uint32_t j = 0; j < c; ++j) {
            uint64_t k = regp[j];
            uint32_t p = atomicAdd(&nselS, 1u);
            if (p < SELCAP) sel[p] = k; else atomicOr(&fbS, 1u);
        }
    }
    __syncthreads();
    uint32_t n = nselS;
    bool fb = (fbS != 0u) || (n < KTOP) || (n > SELCAP);
    __syncthreads();

    if (fb) {
        // ---- exact fallback: 2-pass histogram select over all of conf ----
        if (tid == 0) nselS = 0u;
        for (int b = tid; b < NBINS; b += 1024) hist[b] = 0u;
        __syncthreads();
        for (int f = tid; f < N_PRIORS / 2; f += 1024) {
            float4 c = conf4[f];
            float s0 = score_of(c.x, c.y);
            float s1 = score_of(c.z, c.w);
            if (s0 > 0.9f) atomicAdd(&hist[bin_of(s0)], 1u);
            if (s1 > 0.9f) atomicAdd(&hist[bin_of(s1)], 1u);
        }
        __syncthreads();
        for (int off = 1; off < NBINS; off <<= 1) {
            int b0 = tid, b1 = tid + 1024;
            uint32_t v0 = hist[b0] + ((b0 + off < NBINS) ? hist[b0 + off] : 0u);
            uint32_t v1 = hist[b1] + ((b1 + off < NBINS) ? hist[b1 + off] : 0u);
            __syncthreads();
            hist[b0] = v0; hist[b1] = v1;
            __syncthreads();
        }
        if (hist[tid] >= KTOP) atomicMax(&bmaxS, tid);
        if (hist[tid + 1024] >= KTOP) atomicMax(&bmaxS, tid + 1024);
        __syncthreads();
        int B = bmaxS;
        for (int f = tid; f < N_PRIORS / 2; f += 1024) {
            float4 c = conf4[f];
            float s0 = score_of(c.x, c.y);
            float s1 = score_of(c.z, c.w);
            if (s0 > 0.9f && bin_of(s0) >= B) {
                uint32_t p = atomicAdd(&nselS, 1u);
                if (p < SELCAP) sel[p] = pack_key(s0, 2 * f);
            }
            if (s1 > 0.9f && bin_of(s1) >= B) {
                uint32_t p = atomicAdd(&nselS, 1u);
                if (p < SELCAP) sel[p] = pack_key(s1, 2 * f + 1);
            }
        }
        __syncthreads();
        n = nselS; if (n > SELCAP) n = SELCAP;
        __syncthreads();
    }

    int P = KTOP; while (P < (int)n) P <<= 1;
    for (int t = tid; t < P; t += 1024) if (t >= (int)n) sel[t] = 0ull;
    __syncthreads();

    // ---- bitonic sort, descending (0-padding sinks) ----
    for (int k = 2; k <= P; k <<= 1) {
        for (int j = k >> 1; j > 0; j >>= 1) {
            for (int t = tid; t < P; t += 1024) {
                int ixj = t ^ j;
                if (ixj > t) {
                    uint64_t a = sel[t], b = sel[ixj];
                    bool sw = ((t & k) == 0) ? (a < b) : (a > b);
                    if (sw) { sel[t] = b; sel[ixj] = a; }
                }
            }
            __syncthreads();
        }
    }

    // ---- decode top-512 (exact numpy op order); valid bits via ballot ----
    {
        uint64_t key = (tid < KTOP) ? sel[tid] : 0ull;
        if (tid < KTOP) {
            float4 bb; float area, sc;
            if (key != 0ull) {
                sc = __uint_as_float((uint32_t)(key >> 32));
                int idx  = (int)(~(uint32_t)key);
                float4 l = loc[idx];
                float4 p = priors[idx];
                float cx = p.x + (l.x * 0.1f) * p.z;
                float cy = p.y + (l.y * 0.1f) * p.w;
                float w  = p.z * expf(l.z * 0.2f);
                float h  = p.w * expf(l.w * 0.2f);
                float x1 = cx - w * 0.5f;
                float y1 = cy - h * 0.5f;
                float x2 = x1 + w;
                float y2 = y1 + h;
                x1 *= 2048.0f; y1 *= 2048.0f; x2 *= 2048.0f; y2 *= 2048.0f;
                bb = make_float4(x1, y1, x2, y2);
                area = (x2 - x1 + 1.0f) * (y2 - y1 + 1.0f);
            } else {
                bb = make_float4(0.f, 0.f, 0.f, 0.f); area = 1.f; sc = 0.f;
            }
            bpk[tid] = bb; sar[tid] = area; ssc[tid] = sc;
        }
        uint64_t vb = __ballot(key != 0ull);    // wave w covers cols 64w..64w+63
        if (lane == 0 && wv < 8) keepw0[wv] = vb;
    }
    __syncthreads();   // sel dead; supW (aliasing arena) live from here

    // ---- suppression matrix: 16 waves x 32 rows; lane L owns cols {64c+L}
    //      (contiguous 16B/lane LDS loads). Row bitmasks assembled by ballot:
    //      supW[r*8+c] bit L = (col 64c+L suppressed by row r). ----
    {
        float4 cb0 = bpk[lane +   0], cb1 = bpk[lane +  64];
        float4 cb2 = bpk[lane + 128], cb3 = bpk[lane + 192];
        float4 cb4 = bpk[lane + 256], cb5 = bpk[lane + 320];
        float4 cb6 = bpk[lane + 384], cb7 = bpk[lane + 448];
        // identical formula+inputs as decode -> bit-identical areas
        float ca0 = (cb0.z - cb0.x + 1.0f) * (cb0.w - cb0.y + 1.0f);
        float ca1 = (cb1.z - cb1.x + 1.0f) * (cb1.w - cb1.y + 1.0f);
        float ca2 = (cb2.z - cb2.x + 1.0f) * (cb2.w - cb2.y + 1.0f);
        float ca3 = (cb3.z - cb3.x + 1.0f) * (cb3.w - cb3.y + 1.0f);
        float ca4 = (cb4.z - cb4.x + 1.0f) * (cb4.w - cb4.y + 1.0f);
        float ca5 = (cb5.z - cb5.x + 1.0f) * (cb5.w - cb5.y + 1.0f);
        float ca6 = (cb6.z - cb6.x + 1.0f) * (cb6.w - cb6.y + 1.0f);
        float ca7 = (cb7.z - cb7.x + 1.0f) * (cb7.w - cb7.y + 1.0f);
        #define SUPC(c, CB, CA) do { \
            float xx1 = fmaxf(rb.x, CB.x); float yy1 = fmaxf(rb.y, CB.y); \
            float xx2 = fminf(rb.z, CB.z); float yy2 = fminf(rb.w, CB.w); \
            float ww = fmaxf(xx2 - xx1 + 1.0f, 0.0f); \
            float hh = fmaxf(yy2 - yy1 + 1.0f, 0.0f); \
            float inter = ww * hh; \
            float iou = inter / (ra + (CA) - inter); \
            uint64_t wrd = __ballot(iou > 0.4f && (64 * (c) + lane) > r); \
            if (lane == 0) supW[r * 8 + (c)] = wrd; \
            any |= wrd; } while (0)
        for (int rr = 0; rr < 32; ++rr) {
            int r = wv * 32 + rr;
            float4 rb = bpk[r];     // wave-uniform broadcast
            float ra = sar[r];
            uint64_t any = 0ull;
            SUPC(0, cb0, ca0); SUPC(1, cb1, ca1); SUPC(2, cb2, ca2); SUPC(3, cb3, ca3);
            SUPC(4, cb4, ca4); SUPC(5, cb5, ca5); SUPC(6, cb6, ca6); SUPC(7, cb7, ca7);
            if (lane == 0 && any != 0ull)
                atomicOr(&rowany32[r >> 5], 1u << (r & 31));
        }
        #undef SUPC
    }
    __syncthreads();

    // ---- greedy scan: one thread, bitmask registers; only rows that are
    //      still kept AND suppress something cost anything (rare here) ----
    if (tid == 0) {
        #define RA64(c) (((uint64_t)rowany32[2*(c)]) | (((uint64_t)rowany32[2*(c)+1]) << 32))
        uint64_t kp0 = keepw0[0], kp1 = keepw0[1], kp2 = keepw0[2], kp3 = keepw0[3];
        uint64_t kp4 = keepw0[4], kp5 = keepw0[5], kp6 = keepw0[6], kp7 = keepw0[7];
        #define APPLYROW(i) do { const uint64_t* rp = supW + (size_t)(i) * 8; \
            kp0 &= ~rp[0]; kp1 &= ~rp[1]; kp2 &= ~rp[2]; kp3 &= ~rp[3]; \
            kp4 &= ~rp[4]; kp5 &= ~rp[5]; kp6 &= ~rp[6]; kp7 &= ~rp[7]; } while (0)
        #define CHUNK(c, KPC) do { uint64_t ra = RA64(c); uint64_t m = (KPC) & ra; \
            while (m) { int b = __builtin_ctzll(m); APPLYROW((c) * 64 + b); \
                uint64_t above = (b == 63) ? 0ull : (~0ull << (b + 1)); \
                m = (KPC) & ra & above; } } while (0)
        CHUNK(0, kp0); CHUNK(1, kp1); CHUNK(2, kp2); CHUNK(3, kp3);
        CHUNK(4, kp4); CHUNK(5, kp5); CHUNK(6, kp6); CHUNK(7, kp7);
        keepw[0] = kp0; keepw[1] = kp1; keepw[2] = kp2; keepw[3] = kp3;
        keepw[4] = kp4; keepw[5] = kp5; keepw[6] = kp6; keepw[7] = kp7;
        #undef CHUNK
        #undef APPLYROW
        #undef RA64
    }
    __syncthreads();

    // ---- epilogue: [512,5], boxes /2048 (exact pow2), zeros if suppressed ----
    if (tid < KTOP) {
        const float inv = 1.0f / 2048.0f;
        int kb = (int)((keepw[tid >> 6] >> (tid & 63)) & 1ull);
        float4 bb = bpk[tid];
        float* o = out + tid * 5;
        if (kb) {
            o[0] = bb.x * inv;
            o[1] = bb.y * inv;
            o[2] = bb.z * inv;
            o[3] = bb.w * inv;
            o[4] = ssc[tid];
        } else {
            o[0] = 0.f; o[1] = 0.f; o[2] = 0.f; o[3] = 0.f; o[4] = 0.f;
        }
    }
}

extern "C" void kernel_launch(void* const* d_in, const int* in_sizes, int n_in,
                              void* d_out, int out_size, void* d_ws, size_t ws_size,
                              hipStream_t stream) {
    const float* loc    = (const float*)d_in[0];   // [1,N,4]
    const float* conf   = (const float*)d_in[1];   // [1,N,2]
    const float* priors = (const float*)d_in[2];   // [N,4]
    float* out = (float*)d_out;                    // [512,5]

    uint8_t* ws = (uint8_t*)d_ws;
    uint32_t* blk_cnt = (uint32_t*)ws;             // 8 KB
    uint64_t* stash   = (uint64_t*)(ws + 8192);    // 512 KB

    // no memset needed: blk_cnt fully written by K1; everything else is LDS
    k1_stash<<<K1BLK, 256, 0, stream>>>((const float4*)conf, blk_cnt, stash);
    k2_finish<<<1, 1024, 0, stream>>>((const float4*)loc, (const float4*)priors,
                                      (const float4*)conf, blk_cnt, stash, out);
}